// Round 14
// baseline (175.052 us; speedup 1.0000x reference)
//
#include <hip/hip_runtime.h>
#include <math.h>

#define NREG  8
#define HDIM  128
#define NDEPTH 3
#define TP    128     // points per workgroup tile (2 per lane)
#define W0F   30.0f

// ---------------- routing helpers ----------------

__device__ __forceinline__ int region_of(float X, float Y, float Z, bool* valid) {
    *valid = (X >= 0.f) & (X <= 1.f) & (Y >= 0.f) & (Y <= 1.f) & (Z >= 0.f) & (Z <= 1.f);
    // box r = i*4 + j*2 + k ; ties at 0.5 belong to the lower box (argmax picks first)
    int i = (X > 0.5f) ? 1 : 0;
    int j = (Y > 0.5f) ? 1 : 0;
    int k = (Z > 0.5f) ? 1 : 0;
    return i * 4 + j * 2 + k;
}

// ws int layout: [0..7] counts, [8..16] offsets(exclusive, +total), [20..27] cursors
__global__ __launch_bounds__(256) void k_count(const float* __restrict__ x, int n,
                                               int* __restrict__ ws) {
    __shared__ int h[NREG];
    if (threadIdx.x < NREG) h[threadIdx.x] = 0;
    __syncthreads();
    int i = blockIdx.x * 256 + threadIdx.x;
    if (i < n) {
        float X = x[3*i], Y = x[3*i+1], Z = x[3*i+2];
        bool valid;
        int r = region_of(X, Y, Z, &valid);
        if (valid) atomicAdd(&h[r], 1);
    }
    __syncthreads();
    if (threadIdx.x < NREG) atomicAdd(&ws[threadIdx.x], h[threadIdx.x]);
}

__global__ void k_prefix(int* __restrict__ ws) {
    if (threadIdx.x == 0) {
        int acc = 0;
        for (int r = 0; r < NREG; ++r) {
            ws[8 + r] = acc;      // offsets
            ws[20 + r] = acc;     // cursors
            acc += ws[r];
        }
        ws[8 + NREG] = acc;
    }
}

// Block-aggregated scatter: LDS-rank within block, ONE global atomic per
// (block, region) chunk reservation, then direct stores.
__global__ __launch_bounds__(256) void k_scatter(const float* __restrict__ x, int n,
                                                 int* __restrict__ ws,
                                                 int* __restrict__ idx,
                                                 float* __restrict__ out) {
    __shared__ int hist[NREG];
    __shared__ int base[NREG];
    const int tid = threadIdx.x;
    if (tid < NREG) hist[tid] = 0;
    __syncthreads();
    int i = blockIdx.x * 256 + tid;
    int r = 0, rank = 0;
    bool valid = false;
    if (i < n) {
        float X = x[3*i], Y = x[3*i+1], Z = x[3*i+2];
        r = region_of(X, Y, Z, &valid);
        if (valid) rank = atomicAdd(&hist[r], 1);   // within-block rank
        else out[i] = 0.0f;   // points outside all boxes stay zero
    }
    __syncthreads();
    if (tid < NREG) {
        int c = hist[tid];
        base[tid] = c ? atomicAdd(&ws[20 + tid], c) : 0;
    }
    __syncthreads();
    if (valid) idx[base[r] + rank] = i;
}

// ---------------- fused per-region SIREN MLP ----------------
// r13 skeleton (lane=point, wave=32-ch chunk, weights via wave-uniform
// s_load, acts via ds_read_b32) but TP=128: each lane owns TWO points
// (lane, lane+64). Per j: 2 ds_read_b32 + 32 scalar weights + 64 FMA
// (128 cyc) -> the per-j lgkmcnt(0) drain (smem is out-of-order, shared
// counter with DS) is amortized over 2x the compute, and j+1's s_loads
// get a full 128-cyc shadow. r13 post-mortem: 32 FMA/drain exposed
// ~70-140 cyc of K$-miss latency per j -> VALUBusy 39.5%.

__global__ __launch_bounds__(256) void k_mlp(
    const float* __restrict__ x,
    const float* __restrict__ W_in,  const float* __restrict__ b_in,
    const float* __restrict__ W_h,   const float* __restrict__ b_h,
    const float* __restrict__ W_out, const float* __restrict__ b_out,
    const float* __restrict__ scale, const float* __restrict__ boxes,
    const int* __restrict__ offsets, const int* __restrict__ idx,
    float* __restrict__ out)
{
    __shared__ float hA[HDIM][TP];    // 64 KB [channel][point]
    __shared__ float part[4][TP];     // 2 KB

    const int tid  = threadIdx.x;
    const int wv   = tid >> 6;      // wave id 0..3 -> channel chunk
    const int lane = tid & 63;      // point pair: lane, lane+64
    const int k0   = __builtin_amdgcn_readfirstlane(wv << 5);  // SGPR chunk base

    // map flat block id -> (region, tile)
    int r = -1, base = 0, cnt = 0;
    {
        int bid = blockIdx.x, acc0 = 0;
        for (int rr = 0; rr < NREG; ++rr) {
            int o0 = offsets[rr], o1 = offsets[rr + 1];
            int c = o1 - o0;
            int t = (c + TP - 1) / TP;
            if (bid < acc0 + t) {
                int tile = bid - acc0;
                r = rr; base = o0 + tile * TP; cnt = c - tile * TP;
                break;
            }
            acc0 += t;
        }
    }
    if (r < 0) return;                 // uniform across the block
    if (cnt > TP) cnt = TP;

    // ---- per-lane points & normalized coords (2 points per lane) ----
    int g0 = (lane < cnt)      ? idx[base + lane]      : -1;
    int g1 = (lane + 64 < cnt) ? idx[base + lane + 64] : -1;
    float xn[2][3] = {{0.f,0.f,0.f},{0.f,0.f,0.f}};
    {
        float lo[3], hi[3], sc[3];
        #pragma unroll
        for (int d = 0; d < 3; ++d) {
            lo[d] = boxes[r*6 + d*2 + 0];
            hi[d] = boxes[r*6 + d*2 + 1];
            sc[d] = scale[r*3 + d];
        }
        if (g0 >= 0)
            #pragma unroll
            for (int d = 0; d < 3; ++d)
                xn[0][d] = (2.0f * (x[3*g0+d] - lo[d]) / (hi[d] - lo[d]) - 1.0f) * sc[d];
        if (g1 >= 0)
            #pragma unroll
            for (int d = 0; d < 3; ++d)
                xn[1][d] = (2.0f * (x[3*g1+d] - lo[d]) / (hi[d] - lo[d]) - 1.0f) * sc[d];
    }

    // ---- input layer: hA[k][pt] = sin(30*(xn . W_in[:,k] + b_in[k])) ----
    {
        const float* Wr = W_in + r * 3 * HDIM + k0;   // uniform base -> s_load
        const float* br = b_in + r * HDIM + k0;
        #pragma unroll 8
        for (int c = 0; c < 32; ++c) {
            float w0 = Wr[0*HDIM + c], w1 = Wr[1*HDIM + c], w2 = Wr[2*HDIM + c];
            float bk = br[c];
            float p0 = fmaf(xn[0][0], w0, fmaf(xn[0][1], w1, fmaf(xn[0][2], w2, bk)));
            float p1 = fmaf(xn[1][0], w0, fmaf(xn[1][1], w1, fmaf(xn[1][2], w2, bk)));
            hA[k0 + c][lane]      = sinf(W0F * p0);
            hA[k0 + c][lane + 64] = sinf(W0F * p1);
        }
    }
    __syncthreads();

    // ---- hidden layers ----
    for (int l = 0; l < NDEPTH; ++l) {
        const float* Wl = W_h + ((size_t)(r * NDEPTH + l)) * HDIM * HDIM + k0;
        const float* bl = b_h + (r * NDEPTH + l) * HDIM + k0;
        float acc0[32], acc1[32];
        #pragma unroll
        for (int c = 0; c < 32; ++c) { acc0[c] = bl[c]; acc1[c] = bl[c]; }

        #pragma unroll 2
        for (int j = 0; j < HDIM; ++j) {
            float a0 = hA[j][lane];                     // ds_read_b32
            float a1 = hA[j][lane + 64];                // ds_read_b32
            const float* wrow = Wl + (size_t)j * HDIM;  // uniform row -> s_load
            #pragma unroll
            for (int c = 0; c < 32; ++c) {
                float w = wrow[c];
                acc0[c] = fmaf(w, a0, acc0[c]);         // v_fmac with SGPR weight
                acc1[c] = fmaf(w, a1, acc1[c]);
            }
        }
        // sin in registers, then in-place overwrite of hA
        #pragma unroll
        for (int c = 0; c < 32; ++c) { acc0[c] = sinf(W0F * acc0[c]); acc1[c] = sinf(W0F * acc1[c]); }
        __syncthreads();   // all waves finished reading hA
        #pragma unroll
        for (int c = 0; c < 32; ++c) {
            hA[k0 + c][lane]      = acc0[c];
            hA[k0 + c][lane + 64] = acc1[c];
        }
        __syncthreads();   // writes visible before next layer reads
    }

    // ---- output layer: partial dot per wave chunk, reduce via LDS ----
    {
        const float* Wo = W_out + r * HDIM + k0;       // uniform -> s_load
        float s0 = 0.f, s1 = 0.f;
        #pragma unroll 8
        for (int c = 0; c < 32; ++c) {
            float w = Wo[c];
            s0 = fmaf(w, hA[k0 + c][lane],      s0);
            s1 = fmaf(w, hA[k0 + c][lane + 64], s1);
        }
        part[wv][lane]      = s0;
        part[wv][lane + 64] = s1;
    }
    __syncthreads();
    if (wv == 0) {
        float s0 = part[0][lane] + part[1][lane] + part[2][lane] + part[3][lane]
                 + b_out[r];
        float s1 = part[0][lane+64] + part[1][lane+64] + part[2][lane+64] + part[3][lane+64]
                 + b_out[r];
        if (g0 >= 0) out[g0] = s0;
        if (g1 >= 0) out[g1] = s1;
    }
}

// ---------------- launcher ----------------

extern "C" void kernel_launch(void* const* d_in, const int* in_sizes, int n_in,
                              void* d_out, int out_size, void* d_ws, size_t ws_size,
                              hipStream_t stream) {
    const float* x      = (const float*)d_in[0];
    const float* W_in   = (const float*)d_in[1];
    const float* b_in   = (const float*)d_in[2];
    const float* W_h    = (const float*)d_in[3];
    const float* b_h    = (const float*)d_in[4];
    const float* W_out  = (const float*)d_in[5];
    const float* b_out  = (const float*)d_in[6];
    const float* scale  = (const float*)d_in[7];
    const float* boxes  = (const float*)d_in[8];
    float* out = (float*)d_out;

    int n = in_sizes[0] / 3;
    int* wsi = (int*)d_ws;
    int* idx = (int*)((char*)d_ws + 256);

    hipMemsetAsync(d_ws, 0, 256, stream);

    int nb = (n + 255) / 256;
    hipLaunchKernelGGL(k_count,   dim3(nb), dim3(256), 0, stream, x, n, wsi);
    hipLaunchKernelGGL(k_prefix,  dim3(1),  dim3(64),  0, stream, wsi);
    hipLaunchKernelGGL(k_scatter, dim3(nb), dim3(256), 0, stream, x, n, wsi, idx, out);

    int ntiles = (n + TP - 1) / TP + NREG;
    hipLaunchKernelGGL(k_mlp, dim3(ntiles), dim3(256), 0, stream,
                       x, W_in, b_in, W_h, b_h, W_out, b_out, scale, boxes,
                       wsi + 8, idx, out);
}

// Round 15
// 125.612 us; speedup vs baseline: 1.3936x; 1.3936x over previous
//
#include <hip/hip_runtime.h>
#include <math.h>

#define NREG  8
#define HDIM  128
#define NDEPTH 3
#define TP    64      // points per workgroup tile (= lanes per wave)
#define W0F   30.0f

// ---------------- routing helpers ----------------

__device__ __forceinline__ int region_of(float X, float Y, float Z, bool* valid) {
    *valid = (X >= 0.f) & (X <= 1.f) & (Y >= 0.f) & (Y <= 1.f) & (Z >= 0.f) & (Z <= 1.f);
    // box r = i*4 + j*2 + k ; ties at 0.5 belong to the lower box (argmax picks first)
    int i = (X > 0.5f) ? 1 : 0;
    int j = (Y > 0.5f) ? 1 : 0;
    int k = (Z > 0.5f) ? 1 : 0;
    return i * 4 + j * 2 + k;
}

// ws int layout: [0..7] counts, [8..16] offsets(exclusive, +total), [20..27] cursors
__global__ __launch_bounds__(256) void k_count(const float* __restrict__ x, int n,
                                               int* __restrict__ ws) {
    __shared__ int h[NREG];
    if (threadIdx.x < NREG) h[threadIdx.x] = 0;
    __syncthreads();
    int i = blockIdx.x * 256 + threadIdx.x;
    if (i < n) {
        float X = x[3*i], Y = x[3*i+1], Z = x[3*i+2];
        bool valid;
        int r = region_of(X, Y, Z, &valid);
        if (valid) atomicAdd(&h[r], 1);
    }
    __syncthreads();
    if (threadIdx.x < NREG) atomicAdd(&ws[threadIdx.x], h[threadIdx.x]);
}

__global__ void k_prefix(int* __restrict__ ws) {
    if (threadIdx.x == 0) {
        int acc = 0;
        for (int r = 0; r < NREG; ++r) {
            ws[8 + r] = acc;      // offsets
            ws[20 + r] = acc;     // cursors
            acc += ws[r];
        }
        ws[8 + NREG] = acc;
    }
}

// Block-aggregated scatter: LDS-rank within block, ONE global atomic per
// (block, region) chunk reservation, then direct stores.
__global__ __launch_bounds__(256) void k_scatter(const float* __restrict__ x, int n,
                                                 int* __restrict__ ws,
                                                 int* __restrict__ idx,
                                                 float* __restrict__ out) {
    __shared__ int hist[NREG];
    __shared__ int base[NREG];
    const int tid = threadIdx.x;
    if (tid < NREG) hist[tid] = 0;
    __syncthreads();
    int i = blockIdx.x * 256 + tid;
    int r = 0, rank = 0;
    bool valid = false;
    if (i < n) {
        float X = x[3*i], Y = x[3*i+1], Z = x[3*i+2];
        r = region_of(X, Y, Z, &valid);
        if (valid) rank = atomicAdd(&hist[r], 1);   // within-block rank
        else out[i] = 0.0f;   // points outside all boxes stay zero
    }
    __syncthreads();
    if (tid < NREG) {
        int c = hist[tid];
        base[tid] = c ? atomicAdd(&ws[20 + tid], c) : 0;
    }
    __syncthreads();
    if (valid) idx[base[r] + rank] = i;
}

// ---------------- fused per-region SIREN MLP ----------------
// OCCUPANCY build: 512 threads = 8 waves/block, 16 channels per wave.
// hA[128][64] stays 32KB (shared by all 8 waves). Per wave per j:
// 1 ds_read_b32 (act, conflict-free) + 1 s_load_dwordx16 (16 scalar
// weights) + 16 v_fmac. Occupancy: 2048-thread cap -> 4 blocks/CU =
// 32 waves/CU = 8 waves/SIMD (LDS 4x34.8KB=139KB <= 160KB), vs r13's
// measured ~8 waves/CU. The per-j lgkmcnt(0) drain (~200cyc smem
// latency, out-of-order so no within-wave pipelining) is covered by
// 8 waves x 32cyc issue = 256cyc per SIMD. r14 lesson: per-wave work
// scaling loses to wave-count scaling when latency-bound.

__global__ __launch_bounds__(512) void k_mlp(
    const float* __restrict__ x,
    const float* __restrict__ W_in,  const float* __restrict__ b_in,
    const float* __restrict__ W_h,   const float* __restrict__ b_h,
    const float* __restrict__ W_out, const float* __restrict__ b_out,
    const float* __restrict__ scale, const float* __restrict__ boxes,
    const int* __restrict__ offsets, const int* __restrict__ idx,
    float* __restrict__ out)
{
    __shared__ float hA[HDIM][TP];    // 32 KB [channel][point]
    __shared__ float part[8][TP];     // 2 KB

    const int tid  = threadIdx.x;
    const int wv   = tid >> 6;      // wave id 0..7 -> 16-channel chunk
    const int lane = tid & 63;      // point within tile
    const int k0   = __builtin_amdgcn_readfirstlane(wv << 4);  // SGPR chunk base

    // map flat block id -> (region, tile)
    int r = -1, base = 0, cnt = 0;
    {
        int bid = blockIdx.x, acc0 = 0;
        for (int rr = 0; rr < NREG; ++rr) {
            int o0 = offsets[rr], o1 = offsets[rr + 1];
            int c = o1 - o0;
            int t = (c + TP - 1) / TP;
            if (bid < acc0 + t) {
                int tile = bid - acc0;
                r = rr; base = o0 + tile * TP; cnt = c - tile * TP;
                break;
            }
            acc0 += t;
        }
    }
    if (r < 0) return;                 // uniform across the block
    if (cnt > TP) cnt = TP;

    // ---- per-lane point & normalized coords ----
    int g = (lane < cnt) ? idx[base + lane] : -1;
    float xn0 = 0.f, xn1 = 0.f, xn2 = 0.f;
    if (g >= 0) {
        float lo0 = boxes[r*6 + 0], hi0 = boxes[r*6 + 1];
        float lo1 = boxes[r*6 + 2], hi1 = boxes[r*6 + 3];
        float lo2 = boxes[r*6 + 4], hi2 = boxes[r*6 + 5];
        xn0 = (2.0f * (x[3*g+0] - lo0) / (hi0 - lo0) - 1.0f) * scale[r*3 + 0];
        xn1 = (2.0f * (x[3*g+1] - lo1) / (hi1 - lo1) - 1.0f) * scale[r*3 + 1];
        xn2 = (2.0f * (x[3*g+2] - lo2) / (hi2 - lo2) - 1.0f) * scale[r*3 + 2];
    }

    // ---- input layer: hA[k][lane] = sin(30*(xn . W_in[:,k] + b_in[k])) ----
    {
        const float* Wr = W_in + r * 3 * HDIM + k0;   // uniform base -> s_load
        const float* br = b_in + r * HDIM + k0;
        #pragma unroll
        for (int c = 0; c < 16; ++c) {
            float pre = fmaf(xn0, Wr[0*HDIM + c],
                        fmaf(xn1, Wr[1*HDIM + c],
                        fmaf(xn2, Wr[2*HDIM + c], br[c])));
            hA[k0 + c][lane] = sinf(W0F * pre);
        }
    }
    __syncthreads();

    // ---- hidden layers ----
    for (int l = 0; l < NDEPTH; ++l) {
        const float* Wl = W_h + ((size_t)(r * NDEPTH + l)) * HDIM * HDIM + k0;
        const float* bl = b_h + (r * NDEPTH + l) * HDIM + k0;
        float acc[16];
        #pragma unroll
        for (int c = 0; c < 16; ++c) acc[c] = bl[c];   // bias-init (scalar load)

        #pragma unroll 4
        for (int j = 0; j < HDIM; ++j) {
            float a = hA[j][lane];                      // 1 ds_read_b32 / wave / j
            const float* wrow = Wl + (size_t)j * HDIM;  // uniform row -> s_load_x16
            #pragma unroll
            for (int c = 0; c < 16; ++c)
                acc[c] = fmaf(wrow[c], a, acc[c]);      // v_fmac with SGPR weight
        }
        // sin in registers, then in-place overwrite of hA
        #pragma unroll
        for (int c = 0; c < 16; ++c) acc[c] = sinf(W0F * acc[c]);
        __syncthreads();   // all waves finished reading hA
        #pragma unroll
        for (int c = 0; c < 16; ++c) hA[k0 + c][lane] = acc[c];
        __syncthreads();   // writes visible before next layer reads
    }

    // ---- output layer: partial dot per 16-ch chunk, reduce via LDS ----
    {
        const float* Wo = W_out + r * HDIM + k0;       // uniform -> s_load
        float s = 0.f;
        #pragma unroll
        for (int c = 0; c < 16; ++c)
            s = fmaf(Wo[c], hA[k0 + c][lane], s);
        part[wv][lane] = s;
    }
    __syncthreads();
    if (wv == 0) {
        float s = part[0][lane] + part[1][lane] + part[2][lane] + part[3][lane]
                + part[4][lane] + part[5][lane] + part[6][lane] + part[7][lane]
                + b_out[r];
        if (g >= 0) out[g] = s;
    }
}

// ---------------- launcher ----------------

extern "C" void kernel_launch(void* const* d_in, const int* in_sizes, int n_in,
                              void* d_out, int out_size, void* d_ws, size_t ws_size,
                              hipStream_t stream) {
    const float* x      = (const float*)d_in[0];
    const float* W_in   = (const float*)d_in[1];
    const float* b_in   = (const float*)d_in[2];
    const float* W_h    = (const float*)d_in[3];
    const float* b_h    = (const float*)d_in[4];
    const float* W_out  = (const float*)d_in[5];
    const float* b_out  = (const float*)d_in[6];
    const float* scale  = (const float*)d_in[7];
    const float* boxes  = (const float*)d_in[8];
    float* out = (float*)d_out;

    int n = in_sizes[0] / 3;
    int* wsi = (int*)d_ws;
    int* idx = (int*)((char*)d_ws + 256);

    hipMemsetAsync(d_ws, 0, 256, stream);

    int nb = (n + 255) / 256;
    hipLaunchKernelGGL(k_count,   dim3(nb), dim3(256), 0, stream, x, n, wsi);
    hipLaunchKernelGGL(k_prefix,  dim3(1),  dim3(64),  0, stream, wsi);
    hipLaunchKernelGGL(k_scatter, dim3(nb), dim3(256), 0, stream, x, n, wsi, idx, out);

    int ntiles = (n + TP - 1) / TP + NREG;
    hipLaunchKernelGGL(k_mlp, dim3(ntiles), dim3(512), 0, stream,
                       x, W_in, b_in, W_h, b_h, W_out, b_out, scale, boxes,
                       wsi + 8, idx, out);
}